// Round 5
// baseline (1141.292 us; speedup 1.0000x reference)
//
#include <hip/hip_runtime.h>

// ---------------------------------------------------------------------------
// xp = K*(x @ W_ih^T + b_ih + b_hh)  [bf16 MFMA GEMM, K=2log2e folded in]
// h_t = tanh(xp_t + W_hh h)          [barrier-free scan: 1 wave = 16 batches,
//                                     W_hh in regs, intra-wave LDS transform]
// out = LN(relu(relu(hT W1^T+b1) W2^T+b2))   [same MFMA machinery, fused]
// ---------------------------------------------------------------------------

typedef __bf16 bf16x8 __attribute__((ext_vector_type(8)));
typedef float  f32x4  __attribute__((ext_vector_type(4)));

#define T_STEPS 512
#define I_DIM   2048
#define H_DIM   128
#define B_DIM   64
#define M_TOT   (B_DIM * T_STEPS)
#define KTANH   2.88539008f   // 2*log2(e): tanh(a) = 1 - 2/(exp2(K*a)+1)

// LDS-only barrier (gemm): does NOT drain vmcnt.
#define LDS_BARRIER() asm volatile("s_waitcnt lgkmcnt(0)\n\ts_barrier" ::: "memory")

__device__ __forceinline__ unsigned short f2bf(float f) {
    unsigned int u = __float_as_uint(f);
    u += 0x7FFFu + ((u >> 16) & 1u);
    return (unsigned short)(u >> 16);
}
__device__ __forceinline__ bf16x8 packbf8(float4 lo, float4 hi, float scale) {
    union { bf16x8 v; unsigned short u[8]; } r;
    r.u[0] = f2bf(lo.x * scale); r.u[1] = f2bf(lo.y * scale);
    r.u[2] = f2bf(lo.z * scale); r.u[3] = f2bf(lo.w * scale);
    r.u[4] = f2bf(hi.x * scale); r.u[5] = f2bf(hi.y * scale);
    r.u[6] = f2bf(hi.z * scale); r.u[7] = f2bf(hi.w * scale);
    return r.v;
}
// input pre-scaled by KTANH: tanh = 1 - 2/(exp2(x)+1). 4 ops.
__device__ __forceinline__ float tanhp(float x) {
    float q = __builtin_amdgcn_exp2f(x);
    float r = __builtin_amdgcn_rcpf(q + 1.f);
    return __builtin_fmaf(-2.f, r, 1.f);
}
// pack two fp32 -> bf16x2 (a -> low16, b -> high16), round-half-up
__device__ __forceinline__ unsigned int pack2bf(float a, float b) {
    unsigned int ua = __float_as_uint(a) + 0x8000u;
    unsigned int ub = __float_as_uint(b) + 0x8000u;
    return __builtin_amdgcn_perm(ub, ua, 0x07060302u);
}

// ---------------------------------------------------------------------------
// Kernel 1: xp[M,128] = K*(x@W_ih^T + bias)  (identical structure to R3/R4;
// only the epilogue multiply changed: fma(acc, K, bias*K) — same instr count)
// ---------------------------------------------------------------------------
#define BM  64
#define BK  64
#define LDK 72
#define NKT (I_DIM / BK)

__global__ __launch_bounds__(256) void gemm_xp(
    const float* __restrict__ x, const float* __restrict__ w,
    const float* __restrict__ b_ih, const float* __restrict__ b_hh,
    float* __restrict__ xp)
{
    __shared__ __align__(16) unsigned short As[BM * LDK];
    __shared__ __align__(16) unsigned short Bs[H_DIM * LDK];

    const int tid = threadIdx.x;
    const int m0  = blockIdx.x * BM;
    const int r0  = tid >> 4;
    const int c4  = tid & 15;
    const int lane = tid & 63, wave = tid >> 6;
    const int wm = (wave >> 1) * 32;
    const int wn = (wave & 1) * 64;
    const int l16 = lane & 15, quad = lane >> 4;

    f32x4 acc[2][4] = {};
    float4 ar[2][4], br[2][8];

    auto load_tiles = [&](int s, int k0) {
        #pragma unroll
        for (int i = 0; i < 4; ++i)
            ar[s][i] = *(const float4*)(x + (size_t)(m0 + i * 16 + r0) * I_DIM + k0 + c4 * 4);
        #pragma unroll
        for (int i = 0; i < 8; ++i)
            br[s][i] = *(const float4*)(w + (size_t)(i * 16 + r0) * I_DIM + k0 + c4 * 4);
    };
    auto store_tiles = [&](int s) {
        #pragma unroll
        for (int i = 0; i < 4; ++i) {
            ushort4 v; v.x = f2bf(ar[s][i].x); v.y = f2bf(ar[s][i].y);
                       v.z = f2bf(ar[s][i].z); v.w = f2bf(ar[s][i].w);
            *(ushort4*)(As + (i * 16 + r0) * LDK + c4 * 4) = v;
        }
        #pragma unroll
        for (int i = 0; i < 8; ++i) {
            ushort4 v; v.x = f2bf(br[s][i].x); v.y = f2bf(br[s][i].y);
                       v.z = f2bf(br[s][i].z); v.w = f2bf(br[s][i].w);
            *(ushort4*)(Bs + (i * 16 + r0) * LDK + c4 * 4) = v;
        }
    };
    auto mfma_tile = [&]() {
        #pragma unroll
        for (int kt = 0; kt < 2; ++kt) {
            bf16x8 af[2], bfr[4];
            #pragma unroll
            for (int i = 0; i < 2; ++i)
                af[i] = *(const bf16x8*)(As + (wm + i * 16 + l16) * LDK + kt * 32 + quad * 8);
            #pragma unroll
            for (int j = 0; j < 4; ++j)
                bfr[j] = *(const bf16x8*)(Bs + (wn + j * 16 + l16) * LDK + kt * 32 + quad * 8);
            #pragma unroll
            for (int i = 0; i < 2; ++i)
                #pragma unroll
                for (int j = 0; j < 4; ++j)
                    acc[i][j] = __builtin_amdgcn_mfma_f32_16x16x32_bf16(af[i], bfr[j], acc[i][j], 0, 0, 0);
        }
    };

    load_tiles(0, 0);
    load_tiles(1, BK);

    for (int ii = 0; ii < NKT / 2; ++ii) {
        #pragma unroll
        for (int s = 0; s < 2; ++s) {
            const int i  = ii * 2 + s;
            LDS_BARRIER();
            store_tiles(s);
            const int kn = (i + 2) * BK;
            if (kn < I_DIM) load_tiles(s, kn);
            LDS_BARRIER();
            mfma_tile();
        }
    }

    #pragma unroll
    for (int j = 0; j < 4; ++j) {
        const int col = wn + j * 16 + l16;
        const float biask = (b_ih[col] + b_hh[col]) * KTANH;
        #pragma unroll
        for (int i = 0; i < 2; ++i)
            #pragma unroll
            for (int r = 0; r < 4; ++r) {
                const int row = wm + i * 16 + quad * 4 + r;
                xp[(size_t)(m0 + row) * H_DIM + col] = fmaf(acc[i][j][r], KTANH, biask);
            }
    }
}

// ---------------------------------------------------------------------------
// Kernel 2: barrier-free scan. Grid 4 x 64 threads; wave = 16 batches.
// Lane (q = lane>>4, n = lane&15).
//   A-frags (W_hh*K, regs): aW[i][ks]: row 16i+n, k 32ks+8q+[0..8)
//   B-frags (h, LDS bf16):  hb[ks]:   batch n,  feat 32ks+8q+[0..8)
//   C/D: lane holds D[feat 16i+4q+r][batch n] -> xp C-init has same layout.
// LDS transform store order: dword d (feat 2d,2d+1) of batch n lives at
// dword addr (d>>2)*64 + n*4 + (d&3)  ==> b128 reads are lane-linear.
// ---------------------------------------------------------------------------
#define NBW 16

__global__ __launch_bounds__(64) void rnn_scan(
    const float* __restrict__ xp,
    const float* __restrict__ Whh,
    const float* __restrict__ W1, const float* __restrict__ b1,
    const float* __restrict__ W2, const float* __restrict__ b2,
    const float* __restrict__ gamma, const float* __restrict__ beta,
    float* __restrict__ out)
{
    __shared__ __align__(16) unsigned int hl[16 * 64];   // 4 KB

    const int lane = threadIdx.x;
    const int n = lane & 15, q = lane >> 4;
    const int b0 = blockIdx.x * NBW;

    // W_hh A-frags, pre-scaled by KTANH (128 regs; unified VGPR/AGPR file)
    bf16x8 aW[8][4];
    #pragma unroll
    for (int i = 0; i < 8; ++i) {
        const float* wrow = Whh + (16 * i + n) * H_DIM;
        #pragma unroll
        for (int ks = 0; ks < 4; ++ks) {
            float4 lo = *(const float4*)(wrow + 32 * ks + 8 * q);
            float4 hi = *(const float4*)(wrow + 32 * ks + 8 * q + 4);
            aW[i][ks] = packbf8(lo, hi, KTANH);
        }
    }

    // xp (already scaled by KTANH): lane reads feats 16i+4q+[0..4) of batch n
    const float* xpb = xp + (size_t)(b0 + n) * T_STEPS * H_DIM + 4 * q;

    // depth-2 C-init ring
    f32x4 cin[2][8];
    #pragma unroll
    for (int s = 0; s < 2; ++s)
        #pragma unroll
        for (int i = 0; i < 8; ++i)
            cin[s][i] = *(const f32x4*)(xpb + (size_t)s * H_DIM + 16 * i);

    // h0 = 0
    union { uint4 u; bf16x8 v; } hz; hz.u = make_uint4(0, 0, 0, 0);
    bf16x8 hb[4];
    #pragma unroll
    for (int ks = 0; ks < 4; ++ks) hb[ks] = hz.v;

    const int wb0 = n * 4 + 2 * (q & 1) + (q >> 1) * 64;  // write base (dwords)
    const int rb0 = q * 64 + n * 4;                        // read base (dwords)

    for (int t = 0; t < T_STEPS; ++t) {
        const int s = t & 1;
        f32x4 acc[8];
        // first K-chunk consumes the C-init ring
        #pragma unroll
        for (int i = 0; i < 8; ++i)
            acc[i] = __builtin_amdgcn_mfma_f32_16x16x32_bf16(aW[i][0], hb[0], cin[s][i], 0, 0, 0);
        // refill ring slot s for step t+2 (loads fly during MFMA/tanh)
        {
            int tn = t + 2; if (tn > T_STEPS - 1) tn = T_STEPS - 1;
            #pragma unroll
            for (int i = 0; i < 8; ++i)
                cin[s][i] = *(const f32x4*)(xpb + (size_t)tn * H_DIM + 16 * i);
        }
        #pragma unroll
        for (int ks = 1; ks < 4; ++ks)
            #pragma unroll
            for (int i = 0; i < 8; ++i)
                acc[i] = __builtin_amdgcn_mfma_f32_16x16x32_bf16(aW[i][ks], hb[ks], acc[i], 0, 0, 0);
        // tanh + pack + intra-wave LDS transform (no barrier: same-wave DS order)
        #pragma unroll
        for (int i = 0; i < 8; ++i) {
            uint2 pk;
            pk.x = pack2bf(tanhp(acc[i][0]), tanhp(acc[i][1]));
            pk.y = pack2bf(tanhp(acc[i][2]), tanhp(acc[i][3]));
            *(uint2*)(hl + wb0 + 2 * i * 64) = pk;
        }
        #pragma unroll
        for (int ks = 0; ks < 4; ++ks)
            hb[ks] = *(const bf16x8*)(hl + rb0 + ks * 256);
    }
    // hb = hT B-frags (bf16)

    // ---- FC1: z1 = relu(W1 hT + b1), same machinery (W_hh regs now dead) ----
    bf16x8 wf[8][4];
    #pragma unroll
    for (int i = 0; i < 8; ++i) {
        const float* wrow = W1 + (16 * i + n) * H_DIM;
        #pragma unroll
        for (int ks = 0; ks < 4; ++ks) {
            float4 lo = *(const float4*)(wrow + 32 * ks + 8 * q);
            float4 hi = *(const float4*)(wrow + 32 * ks + 8 * q + 4);
            wf[i][ks] = packbf8(lo, hi, 1.f);
        }
    }
    {
        f32x4 z[8];
        #pragma unroll
        for (int i = 0; i < 8; ++i) {
            float4 bv = *(const float4*)(b1 + 16 * i + 4 * q);
            f32x4 c = {bv.x, bv.y, bv.z, bv.w};
            z[i] = __builtin_amdgcn_mfma_f32_16x16x32_bf16(wf[i][0], hb[0], c, 0, 0, 0);
        }
        #pragma unroll
        for (int ks = 1; ks < 4; ++ks)
            #pragma unroll
            for (int i = 0; i < 8; ++i)
                z[i] = __builtin_amdgcn_mfma_f32_16x16x32_bf16(wf[i][ks], hb[ks], z[i], 0, 0, 0);
        #pragma unroll
        for (int i = 0; i < 8; ++i) {
            uint2 pk;
            pk.x = pack2bf(fmaxf(z[i][0], 0.f), fmaxf(z[i][1], 0.f));
            pk.y = pack2bf(fmaxf(z[i][2], 0.f), fmaxf(z[i][3], 0.f));
            *(uint2*)(hl + wb0 + 2 * i * 64) = pk;
        }
        #pragma unroll
        for (int ks = 0; ks < 4; ++ks)
            hb[ks] = *(const bf16x8*)(hl + rb0 + ks * 256);
    }

    // ---- FC2: z2 = relu(W2 z1 + b2) ----
    #pragma unroll
    for (int i = 0; i < 8; ++i) {
        const float* wrow = W2 + (16 * i + n) * H_DIM;
        #pragma unroll
        for (int ks = 0; ks < 4; ++ks) {
            float4 lo = *(const float4*)(wrow + 32 * ks + 8 * q);
            float4 hi = *(const float4*)(wrow + 32 * ks + 8 * q + 4);
            wf[i][ks] = packbf8(lo, hi, 1.f);
        }
    }
    f32x4 z2[8];
    #pragma unroll
    for (int i = 0; i < 8; ++i) {
        float4 bv = *(const float4*)(b2 + 16 * i + 4 * q);
        f32x4 c = {bv.x, bv.y, bv.z, bv.w};
        z2[i] = __builtin_amdgcn_mfma_f32_16x16x32_bf16(wf[i][0], hb[0], c, 0, 0, 0);
    }
    #pragma unroll
    for (int ks = 1; ks < 4; ++ks)
        #pragma unroll
        for (int i = 0; i < 8; ++i)
            z2[i] = __builtin_amdgcn_mfma_f32_16x16x32_bf16(wf[i][ks], hb[ks], z2[i], 0, 0, 0);

    // ---- LayerNorm: lane holds 32 of batch n's 128 values; reduce over quads
    float sm = 0.f, sq = 0.f;
    #pragma unroll
    for (int i = 0; i < 8; ++i)
        #pragma unroll
        for (int r = 0; r < 4; ++r) {
            float v = fmaxf(z2[i][r], 0.f);
            z2[i][r] = v;
            sm += v; sq += v * v;
        }
    sm += __shfl_xor(sm, 16); sq += __shfl_xor(sq, 16);
    sm += __shfl_xor(sm, 32); sq += __shfl_xor(sq, 32);
    float mu   = sm * (1.f / 128.f);
    float var  = sq * (1.f / 128.f) - mu * mu;
    float rstd = rsqrtf(var + 1e-5f);
    float* op = out + (size_t)(b0 + n) * H_DIM + 4 * q;
    #pragma unroll
    for (int i = 0; i < 8; ++i) {
        float4 g  = *(const float4*)(gamma + 16 * i + 4 * q);
        float4 bt = *(const float4*)(beta  + 16 * i + 4 * q);
        float4 o;
        o.x = fmaf(g.x * rstd, z2[i][0] - mu, bt.x);
        o.y = fmaf(g.y * rstd, z2[i][1] - mu, bt.y);
        o.z = fmaf(g.z * rstd, z2[i][2] - mu, bt.z);
        o.w = fmaf(g.w * rstd, z2[i][3] - mu, bt.w);
        *(float4*)(op + 16 * i) = o;
    }
}

// ---------------------------------------------------------------------------
extern "C" void kernel_launch(void* const* d_in, const int* in_sizes, int n_in,
                              void* d_out, int out_size, void* d_ws, size_t ws_size,
                              hipStream_t stream) {
    const float* x     = (const float*)d_in[0];
    const float* W_ih  = (const float*)d_in[1];
    const float* b_ih  = (const float*)d_in[2];
    const float* W_hh  = (const float*)d_in[3];
    const float* b_hh  = (const float*)d_in[4];
    const float* W1    = (const float*)d_in[5];
    const float* b1    = (const float*)d_in[6];
    const float* W2    = (const float*)d_in[7];
    const float* b2    = (const float*)d_in[8];
    const float* gamma = (const float*)d_in[9];
    const float* beta  = (const float*)d_in[10];
    float* out = (float*)d_out;

    float* xp = (float*)d_ws;

    gemm_xp<<<dim3(M_TOT / BM), dim3(256), 0, stream>>>(x, W_ih, b_ih, b_hh, xp);
    rnn_scan<<<dim3(B_DIM / NBW), dim3(64), 0, stream>>>(xp, W_hh, W1, b1, W2, b2,
                                                         gamma, beta, out);
}